// Round 7
// baseline (157.204 us; speedup 1.0000x reference)
//
#include <hip/hip_runtime.h>
#include <hip/hip_fp8.h>
#include <stdint.h>

#define D_DIM 512
#define B_ROWS 1024
#define C_ROWS 32768
#define NBLK (C_ROWS / 128)   // 256 n-blocks

typedef __attribute__((ext_vector_type(4))) float floatx4;

#define GLOBAL_AS __attribute__((address_space(1)))
#define LDS_AS __attribute__((address_space(3)))

__device__ inline void async_copy16(const unsigned char* g, unsigned char* l) {
    __builtin_amdgcn_global_load_lds((const GLOBAL_AS void*)g, (LDS_AS void*)l, 16, 0, 0);
}

// OCP e4m3 encode/decode via the HIP type (HW cvt on gfx950)
__device__ inline unsigned char f2fp8(float x) {
    __hip_fp8_e4m3 t(x);
    return t.__x;
}
__device__ inline float fp8tof(unsigned char v) {
    __hip_fp8_e4m3 t;
    t.__x = v;
    return (float)t;
}

// A (embeddings) fragment-major layout: 8B unit u = (t16*16 + sidx)*64 +
// quad*16 + fr holds A[row = t16*16 + fr][k = sidx*32 + quad*8 .. +8] (fp8 x8).
// A lane (fr = lane&15, quad = lane>>4) loads fragment (t16, sidx) at byte
// (t16*16 + sidx)*512 + lane*8 -> lane-consecutive global_load_dwordx2.

// Normalize rows of BOTH inputs to norm 3, emit fp8 e4m3. One wave per row.
// Proxies -> row-major Pq (for LDS staging); embeddings -> fragment-major Aq.
// Block 0 additionally zero-inits rowsum/acc/ticket.
__global__ void norm_rows_kernel(const float* __restrict__ prox,
                                 const float* __restrict__ emb,
                                 unsigned char* __restrict__ Pq,
                                 unsigned char* __restrict__ Aq,
                                 float* __restrict__ rowsum,
                                 float* __restrict__ acc,
                                 unsigned* __restrict__ ticket) {
    if (blockIdx.x == 0) {
        for (int i = threadIdx.x; i < B_ROWS; i += 256) rowsum[i] = 0.f;
        if (threadIdx.x == 0) { *acc = 0.f; *ticket = 0u; }
    }
    const int wid = threadIdx.x >> 6;
    const int lane = threadIdx.x & 63;
    int row = blockIdx.x * 4 + wid;
    const float* src;
    const bool is_prox = (row < C_ROWS);
    if (is_prox) {
        src = prox;
    } else {
        row -= C_ROWS;
        src = emb;
    }

    const float4* p = (const float4*)(src + (size_t)row * D_DIM + lane * 8);
    float4 v0 = p[0];
    float4 v1 = p[1];
    float ss = v0.x * v0.x + v0.y * v0.y + v0.z * v0.z + v0.w * v0.w +
               v1.x * v1.x + v1.y * v1.y + v1.z * v1.z + v1.w * v1.w;
#pragma unroll
    for (int off = 1; off < 64; off <<= 1) ss += __shfl_xor(ss, off);
    // norms are ~2.8..23 here, far above the 1e-12 eps in the reference
    const float s = 3.0f * rsqrtf(ss);

    unsigned char q[8];
    q[0] = f2fp8(v0.x * s); q[1] = f2fp8(v0.y * s);
    q[2] = f2fp8(v0.z * s); q[3] = f2fp8(v0.w * s);
    q[4] = f2fp8(v1.x * s); q[5] = f2fp8(v1.y * s);
    q[6] = f2fp8(v1.z * s); q[7] = f2fp8(v1.w * s);
    uint2 packed;
    packed.x = (unsigned)q[0] | ((unsigned)q[1] << 8) |
               ((unsigned)q[2] << 16) | ((unsigned)q[3] << 24);
    packed.y = (unsigned)q[4] | ((unsigned)q[5] << 8) |
               ((unsigned)q[6] << 16) | ((unsigned)q[7] << 24);

    if (is_prox) {
        *(uint2*)(Pq + (size_t)row * D_DIM + lane * 8) = packed;
    } else {
        // fragment-major: sidx = lane>>2, quad = lane&3 (k = lane*8..+8)
        const size_t u = ((size_t)(row >> 4) * 16 + (lane >> 2)) * 64 +
                         (lane & 3) * 16 + (row & 15);
        *(uint2*)(Aq + u * 8) = packed;
    }
}

// 128x128 tile fp8 MFMA GEMM over K=512. B staged in LDS with BK=256
// (2 chunks -> 4 barrier drains/block); A read directly from global in
// fragment-major layout (L2-resident 512 KB), register double-buffered one
// k-step ahead. 16-granule swizzle (g+row)&15 keeps ds_read_b64 conflict-free.
// Epilogue: exp(2*S) row-sums -> LDS -> one global atomicAdd per row.
__global__ void __launch_bounds__(256, 4)
gemm_lse_kernel(const unsigned char* __restrict__ Afrag,
                const unsigned char* __restrict__ Bm,
                float* __restrict__ rowsum) {
    __shared__ unsigned char sB[128 * 256];  // 32 KB (BK=256 fp8)
    __shared__ float red[128];

    const int tid = threadIdx.x;
    const int wid = tid >> 6;
    const int lane = tid & 63;
    const int n0 = blockIdx.x * 128;   // n-fastest grid: adjacent blocks share B
    const int m0t = blockIdx.y * 8;    // m base in t16 units (128 rows)

    if (tid < 128) red[tid] = 0.f;

    // B staging: per call 4 rows x 16 granules; lane -> row (lane>>4),
    // physical granule pg = lane&15. 8 calls/wave/chunk cover the wave's 32 rows.
    const int r4 = lane >> 4;
    const int pg = lane & 15;
    unsigned char* lB = &sB[wid * 32 * 256 + lane * 16];

    // 2x2 wave arrangement, each wave owns 64x64 via 4x4 MFMA 16x16x32 tiles
    const int wmt = (wid >> 1) * 4;  // wave m offset in t16 units
    const int wm = wmt * 16;
    const int wn = (wid & 1) * 64;
    const int fr = lane & 15;
    const int quad = lane >> 4;

    // A fragment pointer: fragment (t, sidx) at Abase + t*8192 + sidx*512
    const unsigned char* Abase =
        Afrag + ((size_t)(m0t + wmt) * 16 * 64 + lane) * 8;

    floatx4 acc[4][4];
    const floatx4 zero = {0.f, 0.f, 0.f, 0.f};
#pragma unroll
    for (int i = 0; i < 4; ++i)
#pragma unroll
        for (int j = 0; j < 4; ++j) acc[i][j] = zero;

    // A register pipeline: preload k-step 0
    long afb[2][4];
#pragma unroll
    for (int t = 0; t < 4; ++t)
        afb[0][t] = *(const long*)(Abase + t * 8192);

    for (int c = 0; c < 2; ++c) {
        // stage B chunk c: k-bytes [c*256, +256)
#pragma unroll
        for (int j = 0; j < 8; ++j) {
            const int row = wid * 32 + j * 4 + r4;
            const int gl = (pg - row) & 15;  // logical granule at this slot
            async_copy16(Bm + (size_t)(n0 + row) * D_DIM + c * 256 + gl * 16,
                         lB + j * 4 * 256);
        }
        __syncthreads();  // drains vmcnt(0): chunk resident

#pragma unroll
        for (int s = 0; s < 8; ++s) {
            const int sidx = c * 8 + s;
            const int cur = sidx & 1;
            if (sidx < 15) {  // prefetch next k-step's A (registers, no barrier)
#pragma unroll
                for (int t = 0; t < 4; ++t)
                    afb[cur ^ 1][t] =
                        *(const long*)(Abase + t * 8192 + (sidx + 1) * 512);
            }
            // B fragment: logical granule g = 2s + (quad>>1), row === fr mod 16
            const int off =
                ((2 * s + (quad >> 1) + fr) & 15) * 16 + (quad & 1) * 8;
            long bf[4];
#pragma unroll
            for (int t = 0; t < 4; ++t)
                bf[t] = *(const long*)&sB[(wn + t * 16 + fr) * 256 + off];
#pragma unroll
            for (int ti = 0; ti < 4; ++ti)
#pragma unroll
                for (int tj = 0; tj < 4; ++tj)
                    acc[ti][tj] = __builtin_amdgcn_mfma_f32_16x16x32_fp8_fp8(
                        afb[cur][ti], bf[tj], acc[ti][tj], 0, 0, 0);
        }
        __syncthreads();  // protect LDS before next chunk overwrites
    }

    // Epilogue: red[m_local] += sum over this block's 128 cols of exp(2*S).
    // C/D layout: col = lane&15, row = quad*4 + reg (dtype-independent)
#pragma unroll
    for (int ti = 0; ti < 4; ++ti) {
        float rs[4] = {0.f, 0.f, 0.f, 0.f};
#pragma unroll
        for (int tj = 0; tj < 4; ++tj)
#pragma unroll
            for (int r = 0; r < 4; ++r)
                rs[r] += __expf(2.0f * acc[ti][tj][r]);
        // sum across the 16 col-lanes (bits 0..3 of lane)
#pragma unroll
        for (int r = 0; r < 4; ++r) {
            rs[r] += __shfl_xor(rs[r], 1);
            rs[r] += __shfl_xor(rs[r], 2);
            rs[r] += __shfl_xor(rs[r], 4);
            rs[r] += __shfl_xor(rs[r], 8);
        }
        if (fr == 0) {
#pragma unroll
            for (int r = 0; r < 4; ++r)
                atomicAdd(&red[wm + ti * 16 + quad * 4 + r], rs[r]);  // LDS atomic
        }
    }
    __syncthreads();
    if (tid < 128) atomicAdd(&rowsum[m0t * 16 + tid], red[tid]);
}

// Fused: per-row positive dot (A fragment-major, P row-major), row loss,
// block partial, grid combine via ticket; last block writes the mean.
__global__ void finalize_kernel(const float* __restrict__ rowsum,
                                const unsigned char* __restrict__ Afrag,
                                const unsigned char* __restrict__ Pq,
                                const int* __restrict__ labels,
                                float* __restrict__ acc,
                                unsigned* __restrict__ ticket,
                                float* __restrict__ out) {
    __shared__ float r4s[4];
    const int tid = threadIdx.x;
    const int wid = tid >> 6;
    const int lane = tid & 63;
    const int b = blockIdx.x * 4 + wid;   // grid = 256 blocks, 4 rows each

    const int l = labels[b];
    // A row b, k = lane*8..+8 in fragment-major
    const size_t u = ((size_t)(b >> 4) * 16 + (lane >> 2)) * 64 +
                     (lane & 3) * 16 + (b & 15);
    uint2 ua = *(const uint2*)(Afrag + u * 8);
    uint2 ub = *(const uint2*)(Pq + (size_t)l * D_DIM + lane * 8);
    const unsigned char* au = (const unsigned char*)&ua;
    const unsigned char* bu = (const unsigned char*)&ub;
    float d = 0.f;
#pragma unroll
    for (int j = 0; j < 8; ++j) d += fp8tof(au[j]) * fp8tof(bu[j]);
#pragma unroll
    for (int off = 1; off < 64; off <<= 1) d += __shfl_xor(d, off);

    if (lane == 0) {
        float p2 = 2.0f * d;
        r4s[wid] = logf(rowsum[b] - __expf(p2)) - p2;  // mask positive class
    }
    __syncthreads();
    if (tid == 0) {
        float bl = r4s[0] + r4s[1] + r4s[2] + r4s[3];
        atomicAdd(acc, bl);
        __threadfence();
        unsigned t = atomicAdd(ticket, 1u);
        if (t == 255u) {  // last block: all 256 contributions are in
            float total = atomicAdd(acc, 0.f);  // coherent device-scope read
            out[0] = total / (float)B_ROWS;
        }
    }
}

extern "C" void kernel_launch(void* const* d_in, const int* in_sizes, int n_in,
                              void* d_out, int out_size, void* d_ws, size_t ws_size,
                              hipStream_t stream) {
    const float* emb = (const float*)d_in[0];    // [1024, 512]
    const float* prox = (const float*)d_in[1];   // [32768, 512]
    const int* labels = (const int*)d_in[2];     // [1024]
    float* out = (float*)d_out;

    char* ws = (char*)d_ws;
    unsigned char* Pq = (unsigned char*)ws;                            // 16 MB
    unsigned char* Aq = Pq + (size_t)C_ROWS * D_DIM;                   // 512 KB
    float* rowsum = (float*)(Aq + (size_t)B_ROWS * D_DIM);             // 4 KB
    float* acc = rowsum + B_ROWS;
    unsigned* ticket = (unsigned*)(acc + 1);

    norm_rows_kernel<<<(C_ROWS + B_ROWS) / 4, 256, 0, stream>>>(
        prox, emb, Pq, Aq, rowsum, acc, ticket);
    gemm_lse_kernel<<<dim3(NBLK, B_ROWS / 128), 256, 0, stream>>>(Aq, Pq, rowsum);
    finalize_kernel<<<B_ROWS / 4, 256, 0, stream>>>(
        rowsum, Aq, Pq, labels, acc, ticket, out);
}

// Round 8
// 139.368 us; speedup vs baseline: 1.1280x; 1.1280x over previous
//
#include <hip/hip_runtime.h>
#include <hip/hip_fp8.h>
#include <stdint.h>

#define D_DIM 512
#define B_ROWS 1024
#define C_ROWS 32768
#define NBLK (C_ROWS / 128)   // 256 n-blocks

typedef __attribute__((ext_vector_type(4))) float floatx4;
typedef __attribute__((ext_vector_type(2))) long longx2;

#define GLOBAL_AS __attribute__((address_space(1)))
#define LDS_AS __attribute__((address_space(3)))

__device__ inline void async_copy16(const unsigned char* g, unsigned char* l) {
    __builtin_amdgcn_global_load_lds((const GLOBAL_AS void*)g, (LDS_AS void*)l, 16, 0, 0);
}

// OCP e4m3 encode/decode via the HIP type (HW cvt on gfx950)
__device__ inline unsigned char f2fp8(float x) {
    __hip_fp8_e4m3 t(x);
    return t.__x;
}
__device__ inline float fp8tof(unsigned char v) {
    __hip_fp8_e4m3 t;
    t.__x = v;
    return (float)t;
}

// Fragment-major-paired layout (BOTH matrices): 16 B unit
//   u = (t16*8 + spair)*64 + quad*16 + fr        (t16 = row/16, fr = row%16)
// holds row[t16*16+fr] k-bytes {sidx=2*spair: quad*8..+8} in the low 8 B and
// {sidx=2*spair+1} in the high 8 B. A lane (fr=lane&15, quad=lane>>4) reads
// its two k-step fragments for (t16, spair) at unit (t16*8+spair)*64 + lane
// -> lane-consecutive 16 B: linear global_load_lds staging AND conflict-free
// stride-1 ds_read_b128 fragment reads.

// Normalize rows of BOTH inputs to norm 3, emit fp8 e4m3 fragment-major.
// One wave per row. Block 0 zero-inits acc/ticket for the finalize combine.
__global__ void norm_rows_kernel(const float* __restrict__ prox,
                                 const float* __restrict__ emb,
                                 unsigned char* __restrict__ Pq,
                                 unsigned char* __restrict__ Aq,
                                 float* __restrict__ acc,
                                 unsigned* __restrict__ ticket) {
    if (blockIdx.x == 0 && threadIdx.x == 0) { *acc = 0.f; *ticket = 0u; }
    const int wid = threadIdx.x >> 6;
    const int lane = threadIdx.x & 63;
    int row = blockIdx.x * 4 + wid;
    const float* src;
    unsigned char* dst;
    if (row < C_ROWS) {
        src = prox; dst = Pq;
    } else {
        row -= C_ROWS;
        src = emb; dst = Aq;
    }

    const float4* p = (const float4*)(src + (size_t)row * D_DIM + lane * 8);
    float4 v0 = p[0];
    float4 v1 = p[1];
    float ss = v0.x * v0.x + v0.y * v0.y + v0.z * v0.z + v0.w * v0.w +
               v1.x * v1.x + v1.y * v1.y + v1.z * v1.z + v1.w * v1.w;
#pragma unroll
    for (int off = 1; off < 64; off <<= 1) ss += __shfl_xor(ss, off);
    // norms are ~2.8..23 here, far above the 1e-12 eps in the reference
    const float s = 3.0f * rsqrtf(ss);

    unsigned char q[8];
    q[0] = f2fp8(v0.x * s); q[1] = f2fp8(v0.y * s);
    q[2] = f2fp8(v0.z * s); q[3] = f2fp8(v0.w * s);
    q[4] = f2fp8(v1.x * s); q[5] = f2fp8(v1.y * s);
    q[6] = f2fp8(v1.z * s); q[7] = f2fp8(v1.w * s);
    uint2 packed;
    packed.x = (unsigned)q[0] | ((unsigned)q[1] << 8) |
               ((unsigned)q[2] << 16) | ((unsigned)q[3] << 24);
    packed.y = (unsigned)q[4] | ((unsigned)q[5] << 8) |
               ((unsigned)q[6] << 16) | ((unsigned)q[7] << 24);

    // lane holds k-bytes lane*8..+8: spair = lane>>3, half = (lane>>2)&1,
    // quad = lane&3
    const size_t u = ((size_t)(row >> 4) * 8 + (lane >> 3)) * 64 +
                     (lane & 3) * 16 + (row & 15);
    *(uint2*)(dst + u * 16 + ((lane >> 2) & 1) * 8) = packed;
}

// 128x128 tile fp8 MFMA GEMM over K=512, BK=128 (4 chunks), both operands
// LDS-staged via linear global_load_lds from the fragment-major layout.
// Fragment reads are stride-1 ds_read_b128 (zero bank conflicts, 2 k-steps
// per read). Epilogue: exp(2*S) row-sums -> part[nblk][m] (coalesced 512 B).
__global__ void __launch_bounds__(256, 4)
gemm_lse_kernel(const unsigned char* __restrict__ Aq,
                const unsigned char* __restrict__ Bq,
                float* __restrict__ part) {
    __shared__ unsigned char sA[16384];  // 8 t16 x 2 spair x 1024 B
    __shared__ unsigned char sB[16384];
    __shared__ float red[128];

    const int tid = threadIdx.x;
    const int wid = tid >> 6;
    const int lane = tid & 63;
    const int n0t = blockIdx.x * 8;   // n base in t16 units (n-fastest grid)
    const int m0t = blockIdx.y * 8;   // m base in t16 units

    if (tid < 128) red[tid] = 0.f;

    // 2x2 wave arrangement, each wave owns 64x64 via 4x4 MFMA 16x16x32 tiles
    const int wmt = (wid >> 1) * 4;
    const int wnt = (wid & 1) * 4;
    const int wm = wmt * 16;
    const int fr = lane & 15;
    const int quad = lane >> 4;

    floatx4 acc[4][4];
    const floatx4 zero = {0.f, 0.f, 0.f, 0.f};
#pragma unroll
    for (int i = 0; i < 4; ++i)
#pragma unroll
        for (int j = 0; j < 4; ++j) acc[i][j] = zero;

    for (int c = 0; c < 4; ++c) {
        // stage chunk c (spairs 2c, 2c+1 for all 8 t16 tiles): wave wid covers
        // t16_local {wid*2, wid*2+1} x spair_local {0,1} -- linear copies.
#pragma unroll
        for (int j = 0; j < 4; ++j) {
            const int tl = wid * 2 + (j >> 1);
            const int sp = j & 1;
            const size_t goA = (((size_t)(m0t + tl) * 8 + 2 * c + sp) * 64 + lane) * 16;
            const size_t goB = (((size_t)(n0t + tl) * 8 + 2 * c + sp) * 64 + lane) * 16;
            const int lo = ((tl * 2 + sp) * 64 + lane) * 16;
            async_copy16(Aq + goA, &sA[lo]);
            async_copy16(Bq + goB, &sB[lo]);
        }
        __syncthreads();  // drains vmcnt(0): chunk resident

#pragma unroll
        for (int p = 0; p < 2; ++p) {  // 2 spairs = 4 k-steps
            longx2 a2[4], b2[4];
#pragma unroll
            for (int t = 0; t < 4; ++t) {
                a2[t] = *(const longx2*)&sA[(((wmt + t) * 2 + p) * 64 + lane) * 16];
                b2[t] = *(const longx2*)&sB[(((wnt + t) * 2 + p) * 64 + lane) * 16];
            }
#pragma unroll
            for (int ti = 0; ti < 4; ++ti)
#pragma unroll
                for (int tj = 0; tj < 4; ++tj)
                    acc[ti][tj] = __builtin_amdgcn_mfma_f32_16x16x32_fp8_fp8(
                        a2[ti][0], b2[tj][0], acc[ti][tj], 0, 0, 0);
#pragma unroll
            for (int ti = 0; ti < 4; ++ti)
#pragma unroll
                for (int tj = 0; tj < 4; ++tj)
                    acc[ti][tj] = __builtin_amdgcn_mfma_f32_16x16x32_fp8_fp8(
                        a2[ti][1], b2[tj][1], acc[ti][tj], 0, 0, 0);
        }
        __syncthreads();  // protect LDS before next chunk overwrites
    }

    // Epilogue: red[m_local] += sum over this block's 128 cols of exp(2*S).
    // C/D layout: col = lane&15, row = quad*4 + reg (dtype-independent)
#pragma unroll
    for (int ti = 0; ti < 4; ++ti) {
        float rs[4] = {0.f, 0.f, 0.f, 0.f};
#pragma unroll
        for (int tj = 0; tj < 4; ++tj)
#pragma unroll
            for (int r = 0; r < 4; ++r)
                rs[r] += __expf(2.0f * acc[ti][tj][r]);
        // sum across the 16 col-lanes (bits 0..3 of lane)
#pragma unroll
        for (int r = 0; r < 4; ++r) {
            rs[r] += __shfl_xor(rs[r], 1);
            rs[r] += __shfl_xor(rs[r], 2);
            rs[r] += __shfl_xor(rs[r], 4);
            rs[r] += __shfl_xor(rs[r], 8);
        }
        if (fr == 0) {
#pragma unroll
            for (int r = 0; r < 4; ++r)
                atomicAdd(&red[wm + ti * 16 + quad * 4 + r], rs[r]);  // LDS atomic
        }
    }
    __syncthreads();
    // part layout [nblk][m]: 128 consecutive floats -> fully coalesced 512 B
    if (tid < 128)
        part[(size_t)blockIdx.x * B_ROWS + m0t * 16 + tid] = red[tid];
}

// Fused: sum 256 partials/row, positive dot (fragment-major reads), row loss,
// grid combine via ticket; last block writes the mean.
__global__ void finalize_kernel(const float* __restrict__ part,
                                const unsigned char* __restrict__ Aq,
                                const unsigned char* __restrict__ Pq,
                                const int* __restrict__ labels,
                                float* __restrict__ acc,
                                unsigned* __restrict__ ticket,
                                float* __restrict__ out) {
    __shared__ float r4s[4];
    const int tid = threadIdx.x;
    const int wid = tid >> 6;
    const int lane = tid & 63;
    const int b = blockIdx.x * 4 + wid;   // grid = 256 blocks, 4 rows each

    // 256 partials for row b, strided by B_ROWS (L2-resident 1 MB)
    float s = 0.f;
#pragma unroll
    for (int k = 0; k < 4; ++k)
        s += part[(size_t)(lane * 4 + k) * B_ROWS + b];

    // positive dot from the same fp8 data the GEMM consumed
    const int l = labels[b];
    const size_t ua_u = ((size_t)(b >> 4) * 8 + (lane >> 3)) * 64 +
                        (lane & 3) * 16 + (b & 15);
    const size_t ub_u = ((size_t)(l >> 4) * 8 + (lane >> 3)) * 64 +
                        (lane & 3) * 16 + (l & 15);
    uint2 ua = *(const uint2*)(Aq + ua_u * 16 + ((lane >> 2) & 1) * 8);
    uint2 ub = *(const uint2*)(Pq + ub_u * 16 + ((lane >> 2) & 1) * 8);
    const unsigned char* au = (const unsigned char*)&ua;
    const unsigned char* bu = (const unsigned char*)&ub;
    float d = 0.f;
#pragma unroll
    for (int j = 0; j < 8; ++j) d += fp8tof(au[j]) * fp8tof(bu[j]);
#pragma unroll
    for (int off = 1; off < 64; off <<= 1) {
        s += __shfl_xor(s, off);
        d += __shfl_xor(d, off);
    }

    if (lane == 0) {
        float p2 = 2.0f * d;
        r4s[wid] = logf(s - __expf(p2)) - p2;  // mask positive class
    }
    __syncthreads();
    if (tid == 0) {
        float bl = r4s[0] + r4s[1] + r4s[2] + r4s[3];
        atomicAdd(acc, bl);
        __threadfence();
        unsigned t = atomicAdd(ticket, 1u);
        if (t == 255u) {  // last block: all 256 contributions are in
            float total = atomicAdd(acc, 0.f);  // coherent device-scope read
            out[0] = total / (float)B_ROWS;
        }
    }
}

extern "C" void kernel_launch(void* const* d_in, const int* in_sizes, int n_in,
                              void* d_out, int out_size, void* d_ws, size_t ws_size,
                              hipStream_t stream) {
    const float* emb = (const float*)d_in[0];    // [1024, 512]
    const float* prox = (const float*)d_in[1];   // [32768, 512]
    const int* labels = (const int*)d_in[2];     // [1024]
    float* out = (float*)d_out;

    char* ws = (char*)d_ws;
    unsigned char* Pq = (unsigned char*)ws;                            // 16 MB
    unsigned char* Aq = Pq + (size_t)C_ROWS * D_DIM;                   // 512 KB
    float* part = (float*)(Aq + (size_t)B_ROWS * D_DIM);               // 1 MB
    float* acc = part + (size_t)NBLK * B_ROWS;
    unsigned* ticket = (unsigned*)(acc + 1);

    norm_rows_kernel<<<(C_ROWS + B_ROWS) / 4, 256, 0, stream>>>(
        prox, emb, Pq, Aq, acc, ticket);
    gemm_lse_kernel<<<dim3(NBLK, B_ROWS / 128), 256, 0, stream>>>(Aq, Pq, part);
    finalize_kernel<<<B_ROWS / 4, 256, 0, stream>>>(
        part, Aq, Pq, labels, acc, ticket, out);
}

// Round 9
// 136.876 us; speedup vs baseline: 1.1485x; 1.0182x over previous
//
#include <hip/hip_runtime.h>
#include <hip/hip_fp8.h>
#include <stdint.h>

#define D_DIM 512
#define B_ROWS 1024
#define C_ROWS 32768
#define NBLK (C_ROWS / 128)   // 256 n-blocks

typedef __attribute__((ext_vector_type(4))) float floatx4;
typedef __attribute__((ext_vector_type(4))) int intx4;
typedef __attribute__((ext_vector_type(8))) int intx8;

#define GLOBAL_AS __attribute__((address_space(1)))
#define LDS_AS __attribute__((address_space(3)))

__device__ inline void async_copy16(const unsigned char* g, unsigned char* l) {
    __builtin_amdgcn_global_load_lds((const GLOBAL_AS void*)g, (LDS_AS void*)l, 16, 0, 0);
}

// OCP e4m3 encode/decode via the HIP type (HW cvt on gfx950)
__device__ inline unsigned char f2fp8(float x) {
    __hip_fp8_e4m3 t(x);
    return t.__x;
}
__device__ inline float fp8tof(unsigned char v) {
    __hip_fp8_e4m3 t;
    t.__x = v;
    return (float)t;
}

// Fragment layout v2 (K=128 MFMA, BOTH matrices). Region R(t16, kc) = 2048 B
// at offset t16*8192 + kc*2048 holds rows [t16*16, +16), k-bytes
// [kc*128, +128). Within a region:
//   byte h*1024 + (quad*16 + fr)*16 + b  (h in {0,1}, b in [0,16))
//   = row[t16*16 + fr], k-byte kc*128 + quad*32 + h*16 + b.
// MFMA lane (fr = lane&15, quad = lane>>4) reads its 32 k-bytes as two
// contiguous stride-16 ds_read_b128 at region + lane*16 and +1024 + lane*16
// (zero bank conflicts), and staging is a pure linear global_load_lds copy.

// Normalize rows of BOTH inputs to norm 3, emit fp8 e4m3 in layout v2.
// One wave per row; lane covers k = lane*8..+8. Block 0 inits acc/ticket.
__global__ void norm_rows_kernel(const float* __restrict__ prox,
                                 const float* __restrict__ emb,
                                 unsigned char* __restrict__ Pq,
                                 unsigned char* __restrict__ Aq,
                                 float* __restrict__ acc,
                                 unsigned* __restrict__ ticket) {
    if (blockIdx.x == 0 && threadIdx.x == 0) { *acc = 0.f; *ticket = 0u; }
    const int wid = threadIdx.x >> 6;
    const int lane = threadIdx.x & 63;
    int row = blockIdx.x * 4 + wid;
    const float* src;
    unsigned char* dst;
    if (row < C_ROWS) {
        src = prox; dst = Pq;
    } else {
        row -= C_ROWS;
        src = emb; dst = Aq;
    }

    const float4* p = (const float4*)(src + (size_t)row * D_DIM + lane * 8);
    float4 v0 = p[0];
    float4 v1 = p[1];
    float ss = v0.x * v0.x + v0.y * v0.y + v0.z * v0.z + v0.w * v0.w +
               v1.x * v1.x + v1.y * v1.y + v1.z * v1.z + v1.w * v1.w;
#pragma unroll
    for (int off = 1; off < 64; off <<= 1) ss += __shfl_xor(ss, off);
    // norms are ~2.8..23 here, far above the 1e-12 eps in the reference
    const float s = 3.0f * rsqrtf(ss);

    unsigned char q[8];
    q[0] = f2fp8(v0.x * s); q[1] = f2fp8(v0.y * s);
    q[2] = f2fp8(v0.z * s); q[3] = f2fp8(v0.w * s);
    q[4] = f2fp8(v1.x * s); q[5] = f2fp8(v1.y * s);
    q[6] = f2fp8(v1.z * s); q[7] = f2fp8(v1.w * s);
    uint2 packed;
    packed.x = (unsigned)q[0] | ((unsigned)q[1] << 8) |
               ((unsigned)q[2] << 16) | ((unsigned)q[3] << 24);
    packed.y = (unsigned)q[4] | ((unsigned)q[5] << 8) |
               ((unsigned)q[6] << 16) | ((unsigned)q[7] << 24);

    // k = lane*8: kc = lane>>4, quad = (lane>>2)&3, h = (lane>>1)&1, b0 = (lane&1)*8
    const size_t addr = (size_t)(row >> 4) * 8192 + (lane >> 4) * 2048 +
                        ((lane >> 1) & 1) * 1024 + ((lane >> 2) & 3) * 256 +
                        (row & 15) * 16 + (lane & 1) * 8;
    *(uint2*)(dst + addr) = packed;
}

// 128x128 tile GEMM over K=512 using MX-scaled fp8 MFMA (16x16x128, unity
// e8m0 scales = pure fp8 matmul at 2x the non-scaled rate). BK=128, 4 chunks,
// both operands LDS-staged via linear global_load_lds from layout v2.
// Fragment reads: contiguous stride-16 ds_read_b128 pairs (zero conflicts).
// Epilogue: exp(2*S) row-sums -> part[nblk][m] (coalesced 512 B).
__global__ void __launch_bounds__(256, 3)
gemm_lse_kernel(const unsigned char* __restrict__ Aq,
                const unsigned char* __restrict__ Bq,
                float* __restrict__ part) {
    __shared__ __align__(16) unsigned char sA[16384];  // 8 t16 x 2048 B
    __shared__ __align__(16) unsigned char sB[16384];
    __shared__ float red[128];

    const int tid = threadIdx.x;
    const int wid = tid >> 6;
    const int lane = tid & 63;
    const int n0t = blockIdx.x * 8;   // n base in t16 units (n-fastest grid)
    const int m0t = blockIdx.y * 8;   // m base in t16 units

    if (tid < 128) red[tid] = 0.f;

    // 2x2 wave arrangement, each wave owns 64x64 via 4x4 MFMA 16x16x128 tiles
    const int wmt = (wid >> 1) * 4;
    const int wnt = (wid & 1) * 4;
    const int wm = wmt * 16;
    const int fr = lane & 15;
    const int quad = lane >> 4;

    floatx4 acc[4][4];
    const floatx4 zero = {0.f, 0.f, 0.f, 0.f};
#pragma unroll
    for (int i = 0; i < 4; ++i)
#pragma unroll
        for (int j = 0; j < 4; ++j) acc[i][j] = zero;

    for (int c = 0; c < 4; ++c) {
        // stage chunk c: wave wid covers t16_local {2*wid, 2*wid+1}; each
        // region is 2048 B = 2 linear 1024-B copies. 8 calls per wave.
#pragma unroll
        for (int j = 0; j < 4; ++j) {
            const int tl = wid * 2 + (j >> 1);
            const int half = j & 1;
            const size_t goA = (size_t)(m0t + tl) * 8192 + c * 2048 + half * 1024;
            const size_t goB = (size_t)(n0t + tl) * 8192 + c * 2048 + half * 1024;
            const int lo = tl * 2048 + half * 1024 + lane * 16;
            async_copy16(Aq + goA + lane * 16, &sA[lo]);
            async_copy16(Bq + goB + lane * 16, &sB[lo]);
        }
        __syncthreads();  // drains vmcnt(0): chunk resident

        // fragments: lane's 32 k-bytes = two 16-B halves at LDS stride 1024
        intx8 a8[4], b8[4];
#pragma unroll
        for (int t = 0; t < 4; ++t) {
            const int oa = (wmt + t) * 2048 + lane * 16;
            const int ob = (wnt + t) * 2048 + lane * 16;
            intx4 alo = *(const intx4*)&sA[oa];
            intx4 ahi = *(const intx4*)&sA[oa + 1024];
            intx4 blo = *(const intx4*)&sB[ob];
            intx4 bhi = *(const intx4*)&sB[ob + 1024];
            a8[t] = __builtin_shufflevector(alo, ahi, 0, 1, 2, 3, 4, 5, 6, 7);
            b8[t] = __builtin_shufflevector(blo, bhi, 0, 1, 2, 3, 4, 5, 6, 7);
        }
#pragma unroll
        for (int ti = 0; ti < 4; ++ti)
#pragma unroll
            for (int tj = 0; tj < 4; ++tj)
                acc[ti][tj] = __builtin_amdgcn_mfma_scale_f32_16x16x128_f8f6f4(
                    a8[ti], b8[tj], acc[ti][tj],
                    0 /*cbsz: A=fp8 e4m3*/, 0 /*blgp: B=fp8 e4m3*/,
                    0, 0x7F /*scale A = 2^0*/, 0, 0x7F /*scale B = 2^0*/);
        __syncthreads();  // protect LDS before next chunk overwrites
    }

    // Epilogue: red[m_local] += sum over this block's 128 cols of exp(2*S).
    // C/D layout: col = lane&15, row = quad*4 + reg (shape-determined, m121-128)
#pragma unroll
    for (int ti = 0; ti < 4; ++ti) {
        float rs[4] = {0.f, 0.f, 0.f, 0.f};
#pragma unroll
        for (int tj = 0; tj < 4; ++tj)
#pragma unroll
            for (int r = 0; r < 4; ++r)
                rs[r] += __expf(2.0f * acc[ti][tj][r]);
        // sum across the 16 col-lanes (bits 0..3 of lane)
#pragma unroll
        for (int r = 0; r < 4; ++r) {
            rs[r] += __shfl_xor(rs[r], 1);
            rs[r] += __shfl_xor(rs[r], 2);
            rs[r] += __shfl_xor(rs[r], 4);
            rs[r] += __shfl_xor(rs[r], 8);
        }
        if (fr == 0) {
#pragma unroll
            for (int r = 0; r < 4; ++r)
                atomicAdd(&red[wm + ti * 16 + quad * 4 + r], rs[r]);  // LDS atomic
        }
    }
    __syncthreads();
    // part layout [nblk][m]: 128 consecutive floats -> fully coalesced 512 B
    if (tid < 128)
        part[(size_t)blockIdx.x * B_ROWS + m0t * 16 + tid] = red[tid];
}

// Fused: sum 256 partials/row, positive dot (layout-v2 reads), row loss,
// grid combine via ticket; last block writes the mean.
__global__ void finalize_kernel(const float* __restrict__ part,
                                const unsigned char* __restrict__ Aq,
                                const unsigned char* __restrict__ Pq,
                                const int* __restrict__ labels,
                                float* __restrict__ acc,
                                unsigned* __restrict__ ticket,
                                float* __restrict__ out) {
    __shared__ float r4s[4];
    const int tid = threadIdx.x;
    const int wid = tid >> 6;
    const int lane = tid & 63;
    const int b = blockIdx.x * 4 + wid;   // grid = 256 blocks, 4 rows each

    // 256 partials for row b, strided by B_ROWS (L2-resident 1 MB)
    float s = 0.f;
#pragma unroll
    for (int k = 0; k < 4; ++k)
        s += part[(size_t)(lane * 4 + k) * B_ROWS + b];

    // positive dot from the same fp8 data the GEMM consumed (layout v2)
    const int l = labels[b];
    const size_t ua_addr = (size_t)(b >> 4) * 8192 + (lane >> 4) * 2048 +
                           ((lane >> 1) & 1) * 1024 + ((lane >> 2) & 3) * 256 +
                           (b & 15) * 16 + (lane & 1) * 8;
    const size_t ub_addr = (size_t)(l >> 4) * 8192 + (lane >> 4) * 2048 +
                           ((lane >> 1) & 1) * 1024 + ((lane >> 2) & 3) * 256 +
                           (l & 15) * 16 + (lane & 1) * 8;
    uint2 ua = *(const uint2*)(Aq + ua_addr);
    uint2 ub = *(const uint2*)(Pq + ub_addr);
    const unsigned char* au = (const unsigned char*)&ua;
    const unsigned char* bu = (const unsigned char*)&ub;
    float d = 0.f;
#pragma unroll
    for (int j = 0; j < 8; ++j) d += fp8tof(au[j]) * fp8tof(bu[j]);
#pragma unroll
    for (int off = 1; off < 64; off <<= 1) {
        s += __shfl_xor(s, off);
        d += __shfl_xor(d, off);
    }

    if (lane == 0) {
        float p2 = 2.0f * d;
        r4s[wid] = logf(s - __expf(p2)) - p2;  // mask positive class
    }
    __syncthreads();
    if (tid == 0) {
        float bl = r4s[0] + r4s[1] + r4s[2] + r4s[3];
        atomicAdd(acc, bl);
        __threadfence();
        unsigned t = atomicAdd(ticket, 1u);
        if (t == 255u) {  // last block: all 256 contributions are in
            float total = atomicAdd(acc, 0.f);  // coherent device-scope read
            out[0] = total / (float)B_ROWS;
        }
    }
}

extern "C" void kernel_launch(void* const* d_in, const int* in_sizes, int n_in,
                              void* d_out, int out_size, void* d_ws, size_t ws_size,
                              hipStream_t stream) {
    const float* emb = (const float*)d_in[0];    // [1024, 512]
    const float* prox = (const float*)d_in[1];   // [32768, 512]
    const int* labels = (const int*)d_in[2];     // [1024]
    float* out = (float*)d_out;

    char* ws = (char*)d_ws;
    unsigned char* Pq = (unsigned char*)ws;                            // 16 MB
    unsigned char* Aq = Pq + (size_t)C_ROWS * D_DIM;                   // 512 KB
    float* part = (float*)(Aq + (size_t)B_ROWS * D_DIM);               // 1 MB
    float* acc = part + (size_t)NBLK * B_ROWS;
    unsigned* ticket = (unsigned*)(acc + 1);

    norm_rows_kernel<<<(C_ROWS + B_ROWS) / 4, 256, 0, stream>>>(
        prox, emb, Pq, Aq, acc, ticket);
    gemm_lse_kernel<<<dim3(NBLK, B_ROWS / 128), 256, 0, stream>>>(Aq, Pq, part);
    finalize_kernel<<<B_ROWS / 4, 256, 0, stream>>>(
        part, Aq, Pq, labels, acc, ticket, out);
}